// Round 12
// baseline (748.854 us; speedup 1.0000x reference)
//
#include <hip/hip_runtime.h>

typedef unsigned short u16;
typedef unsigned int u32;
typedef u16 u16x4 __attribute__((ext_vector_type(4)));
typedef u16 u16x8 __attribute__((ext_vector_type(8)));
typedef __bf16 bf16x8 __attribute__((ext_vector_type(8)));
typedef float f32x4 __attribute__((ext_vector_type(4)));
typedef float f32x16 __attribute__((ext_vector_type(16)));

static __device__ __forceinline__ u16 f2bf(float f) {
  union { float f; u32 u; } x; x.f = f;
  u32 r = x.u + 0x7fffu + ((x.u >> 16) & 1u);
  return (u16)(r >> 16);
}
static __device__ __forceinline__ u32 packbf(float a, float b) {
  union { u32 u; __bf16 h[2]; } x; x.h[0] = (__bf16)a; x.h[1] = (__bf16)b; return x.u;
}
static __device__ __forceinline__ void pl32swap(u32& a, u32& b) {
  asm volatile("v_permlane32_swap_b32 %0, %1" : "+v"(a), "+v"(b));
}
static __device__ __forceinline__ void gload16(const void* g, void* l) {
  __builtin_amdgcn_global_load_lds((const __attribute__((address_space(1))) unsigned int*)g,
                                   (__attribute__((address_space(3))) unsigned int*)l, 16, 0, 0);
}

// ---------------- fused fp32->bf16 casts + K_xl(+pos) build ----------------
__global__ __launch_bounds__(256) void cvt_fuse(const float* __restrict__ q, const float* __restrict__ wqkv_f,
                                                const float* __restrict__ wproj_f, const float* __restrict__ k_xl,
                                                const float* __restrict__ pos, u16* __restrict__ qbf,
                                                u16* __restrict__ wqkv, u16* __restrict__ wproj,
                                                u16* __restrict__ khxl, float sc) {
  int i = blockIdx.x * 256 + threadIdx.x;
  if (i < 2097152) {
    const float* src;
    u16* dst;
    int j;
    float s = 1.0f;
    if (i < 1048576) { src = q; dst = qbf; j = i; }
    else if (i < 1835008) { j = i - 1048576; src = wqkv_f; dst = wqkv; if (j < 262144) s = sc; }
    else { j = i - 1835008; src = wproj_f; dst = wproj; }
    float4 v = reinterpret_cast<const float4*>(src)[j];
    u16x4 o; o[0] = f2bf(v.x * s); o[1] = f2bf(v.y * s); o[2] = f2bf(v.z * s); o[3] = f2bf(v.w * s);
    reinterpret_cast<u16x4*>(dst)[j] = o;
  } else {
    int idx = i - 2097152;
    int d8 = idx & 7;
    int s = (idx >> 3) & 2047;
    int bh = idx >> 14;
    int b = bh >> 4, h = bh & 15;
    size_t src = ((size_t)(b * 2048 + s)) * 1024 + h * 64 + d8 * 8;
    size_t ps = ((size_t)s) * 1024 + h * 64 + d8 * 8;
    float4 a0 = *(const float4*)&k_xl[src];
    float4 a1 = *(const float4*)&k_xl[src + 4];
    float4 p0 = *(const float4*)&pos[ps];
    float4 p1 = *(const float4*)&pos[ps + 4];
    u16x8 o;
    o[0] = f2bf(a0.x + p0.x); o[1] = f2bf(a0.y + p0.y); o[2] = f2bf(a0.z + p0.z); o[3] = f2bf(a0.w + p0.w);
    o[4] = f2bf(a1.x + p1.x); o[5] = f2bf(a1.y + p1.y); o[6] = f2bf(a1.z + p1.z); o[7] = f2bf(a1.w + p1.w);
    *(u16x8*)&khxl[((size_t)bh * 2048 + s) * 64 + d8 * 8] = o;
  }
}

// ---------------- GEMM: 2-phase dbuf pipeline, BK=64, gload_lds + XOR swizzle ----------------
template <int OUT_BF16>
__global__ __launch_bounds__(256, 2) void gemm_bt3(const u16* __restrict__ A, const u16* __restrict__ B,
                                                   void* __restrict__ Cout, int M, int N, int K) {
  __shared__ alignas(128) u16 As[2][8192];
  __shared__ alignas(128) u16 Bs[2][8192];
  const int tid = threadIdx.x;
  const int m0 = blockIdx.y * 128, n0 = blockIdx.x * 128;
  const int wid = tid >> 6, lane = tid & 63;
  const int lm = lane & 15, lg = lane >> 4;
  const int wm = (wid >> 1) * 64, wn = (wid & 1) * 64;
  int srow[4], scol[4], dsto[4];
#pragma unroll
  for (int i = 0; i < 4; i++) {
    int li = tid + i * 256;
    srow[i] = li >> 3;
    scol[i] = ((li & 7) ^ (srow[i] & 7)) * 8;
    dsto[i] = (i * 256 + wid * 64) * 8;
  }
  f32x4 acc[4][4] = {};
#pragma unroll
  for (int i = 0; i < 4; i++) {
    gload16(&A[(size_t)(m0 + srow[i]) * K + scol[i]], &As[0][dsto[i]]);
    gload16(&B[(size_t)(n0 + srow[i]) * K + scol[i]], &Bs[0][dsto[i]]);
  }
  int cur = 0;
  for (int k0 = 0; k0 < K; k0 += 64) {
    __syncthreads();
    if (k0 + 64 < K) {
#pragma unroll
      for (int i = 0; i < 4; i++) {
        gload16(&A[(size_t)(m0 + srow[i]) * K + k0 + 64 + scol[i]], &As[cur ^ 1][dsto[i]]);
        gload16(&B[(size_t)(n0 + srow[i]) * K + k0 + 64 + scol[i]], &Bs[cur ^ 1][dsto[i]]);
      }
    }
    const u16* Asb = As[cur];
    const u16* Bsb = Bs[cur];
#pragma unroll
    for (int ks = 0; ks < 2; ks++) {
      bf16x8 af[4], bfr[4];
#pragma unroll
      for (int mi = 0; mi < 4; mi++) {
        int row = wm + mi * 16 + lm;
        af[mi] = *(const bf16x8*)&Asb[row * 64 + (((ks * 4 + lg) ^ (row & 7)) << 3)];
      }
#pragma unroll
      for (int ni = 0; ni < 4; ni++) {
        int row = wn + ni * 16 + lm;
        bfr[ni] = *(const bf16x8*)&Bsb[row * 64 + (((ks * 4 + lg) ^ (row & 7)) << 3)];
      }
#pragma unroll
      for (int mi = 0; mi < 4; mi++)
#pragma unroll
        for (int ni = 0; ni < 4; ni++)
          acc[mi][ni] = __builtin_amdgcn_mfma_f32_16x16x32_bf16(af[mi], bfr[ni], acc[mi][ni], 0, 0, 0);
    }
    cur ^= 1;
  }
#pragma unroll
  for (int mi = 0; mi < 4; mi++)
#pragma unroll
    for (int ni = 0; ni < 4; ni++)
#pragma unroll
      for (int r = 0; r < 4; r++) {
        int row = m0 + wm + mi * 16 + lg * 4 + r;
        int col = n0 + wn + ni * 16 + lm;
        if (OUT_BF16) ((u16*)Cout)[(size_t)row * N + col] = f2bf(acc[mi][ni][r]);
        else          ((float*)Cout)[(size_t)row * N + col] = acc[mi][ni][r];
      }
}

// ---------------- Vt[b][h][d][s] (transposed V) ----------------
__global__ __launch_bounds__(256) void build_vt(const float* __restrict__ v_xl, const u16* __restrict__ qkvb,
                                                u16* __restrict__ Vt) {
  __shared__ u16 tile[64][72];
  const int bh = blockIdx.y, b = bh >> 4, h = bh & 15;
  const int s0 = blockIdx.x * 64;
  const int tid = threadIdx.x;
  {
    int sl = tid >> 2;
    int dseg = (tid & 3) * 16;
    if (s0 < 2048) {
      const float* src = v_xl + ((size_t)(b * 2048 + s0 + sl)) * 1024 + h * 64 + dseg;
#pragma unroll
      for (int j = 0; j < 16; j += 4) {
        float4 v = *(const float4*)&src[j];
        tile[sl][dseg + j] = f2bf(v.x);
        tile[sl][dseg + j + 1] = f2bf(v.y);
        tile[sl][dseg + j + 2] = f2bf(v.z);
        tile[sl][dseg + j + 3] = f2bf(v.w);
      }
    } else {
      const u16* src = qkvb + ((size_t)(b * 2048 + s0 - 2048 + sl)) * 3072 + 2048 + h * 64 + dseg;
      *(u16x8*)&tile[sl][dseg] = *(const u16x8*)&src[0];
      *(u16x8*)&tile[sl][dseg + 8] = *(const u16x8*)&src[8];
    }
  }
  __syncthreads();
  {
    int d = tid >> 2;
    int sseg = (tid & 3) * 16;
    u16* dst = Vt + ((size_t)bh * 64 + d) * 4096 + s0 + sseg;
    u16x8 o0, o1;
#pragma unroll
    for (int j = 0; j < 8; j++) { o0[j] = tile[sseg + j][d]; o1[j] = tile[sseg + 8 + j][d]; }
    *(u16x8*)&dst[0] = o0;
    *(u16x8*)&dst[8] = o1;
  }
}

// ---------------- flash attention v12: KVBLK=128 (R8 skeleton) x dual-q waves (R10 body) ----------------
// grid (T/128, B*H) XCD-swizzled; 512 thr, 8 waves (qt, ks, subw). Wave = 64 q (2 q-blocks) x keys
// [subw*64+ks*32, +32) of each 128-key tile. R8's exact staging/loop; R10's exact COMPUTE; 2-step
// LDS combine of the 4 partials per q-group.
__global__ __launch_bounds__(512, 4) void attn_fwd12(const u16* __restrict__ qkvb, const u16* __restrict__ khxl,
                                                     const u16* __restrict__ vt, u16* __restrict__ Y) {
  const int T = 2048;
  __shared__ alignas(128) u16 lds[32768];  // u16 idx: KA=0 KB=8192 VA=16384 VB=24576 (64KB)
  __shared__ float CBl[384];
  const int dd = blockIdx.x + (blockIdx.y << 4);  // [0,512)
  const int w = ((dd & 7) << 6) + (dd >> 3);      // bijective XCD-chunked swizzle
  const int bh = w >> 4;
  const int q0 = (w & 15) * 128;
  const int tid = threadIdx.x, wid = tid >> 6, lane = tid & 63;
  const int qt = wid >> 2, ks = (wid >> 1) & 1, subw = wid & 1;
  const int l31 = lane & 31, hi = lane >> 5;
  const int sw = l31 & 7;
  const int b = bh >> 4, h = bh & 15;
  // Q fragments for both q-blocks (scale*log2e folded into W_qkv Q-rows)
  bf16x8 qf0[4], qf1[4];
  {
    const u16* Qp0 = qkvb + (size_t)(b * T + q0 + qt * 64 + l31) * 3072 + h * 64;
    const u16* Qp1 = Qp0 + (size_t)32 * 3072;
#pragma unroll
    for (int c = 0; c < 4; c++) {
      qf0[c] = *(const bf16x8*)&Qp0[c * 16 + hi * 8];
      qf1[c] = *(const bf16x8*)&Qp1[c * 16 + hi * 8];
    }
  }
  // staging (exact R8): 512 threads, srow in [0,64); 2 K-chunks + 2 V-chunks per thread per tile
  const int srow = tid >> 3, pc = tid & 7;
  const int scol = (pc ^ (srow & 7)) * 8;
  const u16* kxl_s = khxl + ((size_t)bh * 2048 + srow) * 64 + scol;                 // +4096: rows+64; tile +8192
  const u16* knew_s = qkvb + (size_t)(b * T + srow) * 3072 + 1024 + h * 64 + scol;  // +196608: rows+64; tile +393216
  const u16* v_s = vt + ((size_t)bh * 64 + srow) * 4096 + scol;                     // +64: keys+64; tile +128
  const int kd = tid * 8;
  f32x16 acc00 = {0.0f}, acc01 = {0.0f}, acc10 = {0.0f}, acc11 = {0.0f};
  float lrun0 = 0.0f, lrun1 = 0.0f;
  const int krow = subw * 64 + ks * 32 + l31;

#define STAGE_XL(KO, VO)                              \
  do {                                                \
    gload16(kxl_s, &lds[(KO) + kd]);                  \
    gload16(kxl_s + 4096, &lds[(KO) + 4096 + kd]);    \
    gload16(v_s, &lds[(VO) + kd]);                    \
    gload16(v_s + 64, &lds[(VO) + 4096 + kd]);        \
    kxl_s += 8192; v_s += 128;                        \
  } while (0)
#define STAGE_NEW(KO, VO)                             \
  do {                                                \
    gload16(knew_s, &lds[(KO) + kd]);                 \
    gload16(knew_s + 196608, &lds[(KO) + 4096 + kd]); \
    gload16(v_s, &lds[(VO) + kd]);                    \
    gload16(v_s + 64, &lds[(VO) + 4096 + kd]);        \
    knew_s += 393216; v_s += 128;                     \
  } while (0)
#define COMPUTE(KO, VO)                                                             \
  do {                                                                              \
    const int _vo = (VO) + subw * 4096;                                             \
    bf16x8 kf0 = *(const bf16x8*)&lds[(KO) + krow * 64 + (((0 + hi) ^ sw) << 3)];   \
    bf16x8 kf1 = *(const bf16x8*)&lds[(KO) + krow * 64 + (((2 + hi) ^ sw) << 3)];   \
    bf16x8 kf2 = *(const bf16x8*)&lds[(KO) + krow * 64 + (((4 + hi) ^ sw) << 3)];   \
    bf16x8 kf3 = *(const bf16x8*)&lds[(KO) + krow * 64 + (((6 + hi) ^ sw) << 3)];   \
    f32x16 s0 = {0.0f}, s1 = {0.0f};                                                \
    __builtin_amdgcn_s_setprio(1);                                                  \
    s0 = __builtin_amdgcn_mfma_f32_32x32x16_bf16(kf0, qf0[0], s0, 0, 0, 0);         \
    s1 = __builtin_amdgcn_mfma_f32_32x32x16_bf16(kf0, qf1[0], s1, 0, 0, 0);         \
    s0 = __builtin_amdgcn_mfma_f32_32x32x16_bf16(kf1, qf0[1], s0, 0, 0, 0);         \
    s1 = __builtin_amdgcn_mfma_f32_32x32x16_bf16(kf1, qf1[1], s1, 0, 0, 0);         \
    s0 = __builtin_amdgcn_mfma_f32_32x32x16_bf16(kf2, qf0[2], s0, 0, 0, 0);         \
    s1 = __builtin_amdgcn_mfma_f32_32x32x16_bf16(kf2, qf1[2], s1, 0, 0, 0);         \
    s0 = __builtin_amdgcn_mfma_f32_32x32x16_bf16(kf3, qf0[3], s0, 0, 0, 0);         \
    s1 = __builtin_amdgcn_mfma_f32_32x32x16_bf16(kf3, qf1[3], s1, 0, 0, 0);         \
    __builtin_amdgcn_s_setprio(0);                                                  \
    u32 w40[4][2], w41[4][2];                                                       \
    _Pragma("unroll")                                                               \
    for (int r = 0; r < 16; r++) s0[r] = __builtin_amdgcn_exp2f(s0[r]);             \
    lrun0 += (((s0[0] + s0[1]) + (s0[2] + s0[3])) + ((s0[4] + s0[5]) + (s0[6] + s0[7])))         \
           + (((s0[8] + s0[9]) + (s0[10] + s0[11])) + ((s0[12] + s0[13]) + (s0[14] + s0[15])));  \
    _Pragma("unroll")                                                               \
    for (int g = 0; g < 4; g++) {                                                   \
      w40[g][0] = packbf(s0[4 * g + 0], s0[4 * g + 1]);                             \
      w40[g][1] = packbf(s0[4 * g + 2], s0[4 * g + 3]);                             \
    }                                                                               \
    _Pragma("unroll")                                                               \
    for (int r = 0; r < 16; r++) s1[r] = __builtin_amdgcn_exp2f(s1[r]);             \
    lrun1 += (((s1[0] + s1[1]) + (s1[2] + s1[3])) + ((s1[4] + s1[5]) + (s1[6] + s1[7])))         \
           + (((s1[8] + s1[9]) + (s1[10] + s1[11])) + ((s1[12] + s1[13]) + (s1[14] + s1[15])));  \
    _Pragma("unroll")                                                               \
    for (int g = 0; g < 4; g++) {                                                   \
      w41[g][0] = packbf(s1[4 * g + 0], s1[4 * g + 1]);                             \
      w41[g][1] = packbf(s1[4 * g + 2], s1[4 * g + 3]);                             \
    }                                                                               \
    __builtin_amdgcn_s_setprio(1);                                                  \
    _Pragma("unroll")                                                               \
    for (int m2 = 0; m2 < 2; m2++) {                                                \
      int cg = 2 * (ks * 2 + m2) + hi;                                              \
      bf16x8 v0 = *(const bf16x8*)&lds[_vo + l31 * 64 + ((cg ^ sw) << 3)];          \
      bf16x8 v1 = *(const bf16x8*)&lds[_vo + (32 + l31) * 64 + ((cg ^ sw) << 3)];   \
      u32 A0 = w40[2 * m2][0], A2 = w40[2 * m2 + 1][0];                             \
      pl32swap(A0, A2);                                                             \
      u32 A1 = w40[2 * m2][1], A3 = w40[2 * m2 + 1][1];                             \
      pl32swap(A1, A3);                                                             \
      union { u32 u[4]; bf16x8 v; } pf0;                                            \
      pf0.u[0] = A0; pf0.u[1] = A1; pf0.u[2] = A2; pf0.u[3] = A3;                   \
      acc00 = __builtin_amdgcn_mfma_f32_32x32x16_bf16(v0, pf0.v, acc00, 0, 0, 0);   \
      acc01 = __builtin_amdgcn_mfma_f32_32x32x16_bf16(v1, pf0.v, acc01, 0, 0, 0);   \
      u32 B0 = w41[2 * m2][0], B2 = w41[2 * m2 + 1][0];                             \
      pl32swap(B0, B2);                                                             \
      u32 B1 = w41[2 * m2][1], B3 = w41[2 * m2 + 1][1];                             \
      pl32swap(B1, B3);                                                             \
      union { u32 u[4]; bf16x8 v; } pf1;                                            \
      pf1.u[0] = B0; pf1.u[1] = B1; pf1.u[2] = B2; pf1.u[3] = B3;                   \
      acc10 = __builtin_amdgcn_mfma_f32_32x32x16_bf16(v0, pf1.v, acc10, 0, 0, 0);   \
      acc11 = __builtin_amdgcn_mfma_f32_32x32x16_bf16(v1, pf1.v, acc11, 0, 0, 0);   \
    }                                                                               \
    __builtin_amdgcn_s_setprio(0);                                                  \
  } while (0)

  // 16 XL tiles of 128 keys, then 16 NEW tiles (exact R8 schedule)
  STAGE_XL(0, 16384);
  for (int j = 0; j < 7; ++j) {
    __syncthreads();
    STAGE_XL(8192, 24576);
    COMPUTE(0, 16384);
    __syncthreads();
    STAGE_XL(0, 16384);
    COMPUTE(8192, 24576);
  }
  __syncthreads();
  STAGE_XL(8192, 24576);   // XL 15
  COMPUTE(0, 16384);       // XL 14
  __syncthreads();
  STAGE_NEW(0, 16384);     // NEW 0
  COMPUTE(8192, 24576);    // XL 15
  for (int j = 0; j < 7; ++j) {
    __syncthreads();
    STAGE_NEW(8192, 24576);
    COMPUTE(0, 16384);
    __syncthreads();
    STAGE_NEW(0, 16384);
    COMPUTE(8192, 24576);
  }
  __syncthreads();
  STAGE_NEW(8192, 24576);  // NEW 15
  COMPUTE(0, 16384);       // NEW 14
  __syncthreads();
  COMPUTE(8192, 24576);    // NEW 15
#undef STAGE_XL
#undef STAGE_NEW
#undef COMPUTE

  // ---- 2-step combine of 4 partials per q-group, then normalize + transpose + store ----
  float lt0 = lrun0 + __shfl_xor(lrun0, 32);
  float lt1 = lrun1 + __shfl_xor(lrun1, 32);
  __syncthreads();
  float* CB = (float*)lds;  // step1: 8 groups x 64 lanes x 32 f32 = 64 KB
  // step 1: subw=1 publish -> subw=0 absorb (groups keyed by (qt,qb,ks))
  if (subw) {
    float* p0 = CB + (size_t)(((qt * 2 + 0) * 2 + ks) * 64 + lane) * 32;
    float* p1 = CB + (size_t)(((qt * 2 + 1) * 2 + ks) * 64 + lane) * 32;
#pragma unroll
    for (int j = 0; j < 8; j++) {
      f32x4 u0, u1;
#pragma unroll
      for (int e = 0; e < 4; e++) {
        u0[e] = (j < 4) ? acc00[4 * j + e] : acc01[4 * (j - 4) + e];
        u1[e] = (j < 4) ? acc10[4 * j + e] : acc11[4 * (j - 4) + e];
      }
      *(f32x4*)&p0[4 * (j ^ (lane & 7))] = u0;
      *(f32x4*)&p1[4 * (j ^ (lane & 7))] = u1;
    }
    if (hi == 0) {
      CBl[((qt * 2 + 0) * 2 + ks) * 32 + l31] = lt0;
      CBl[((qt * 2 + 1) * 2 + ks) * 32 + l31] = lt1;
    }
  }
  __syncthreads();
  if (!subw) {
    const float* p0 = CB + (size_t)(((qt * 2 + 0) * 2 + ks) * 64 + lane) * 32;
    const float* p1 = CB + (size_t)(((qt * 2 + 1) * 2 + ks) * 64 + lane) * 32;
#pragma unroll
    for (int j = 0; j < 8; j++) {
      f32x4 u0 = *(const f32x4*)&p0[4 * (j ^ (lane & 7))];
      f32x4 u1 = *(const f32x4*)&p1[4 * (j ^ (lane & 7))];
#pragma unroll
      for (int e = 0; e < 4; e++) {
        if (j < 4) { acc00[4 * j + e] += u0[e]; acc10[4 * j + e] += u1[e]; }
        else       { acc01[4 * (j - 4) + e] += u0[e]; acc11[4 * (j - 4) + e] += u1[e]; }
      }
    }
    lt0 += CBl[((qt * 2 + 0) * 2 + ks) * 32 + l31];
    lt1 += CBl[((qt * 2 + 1) * 2 + ks) * 32 + l31];
  }
  __syncthreads();
  // step 2: ks=1 (subw=0) publish -> ks=0 absorb (groups keyed by (qt,qb))
  if (!subw && ks) {
    float* p0 = CB + (size_t)((qt * 2 + 0) * 64 + lane) * 32;
    float* p1 = CB + (size_t)((qt * 2 + 1) * 64 + lane) * 32;
#pragma unroll
    for (int j = 0; j < 8; j++) {
      f32x4 u0, u1;
#pragma unroll
      for (int e = 0; e < 4; e++) {
        u0[e] = (j < 4) ? acc00[4 * j + e] : acc01[4 * (j - 4) + e];
        u1[e] = (j < 4) ? acc10[4 * j + e] : acc11[4 * (j - 4) + e];
      }
      *(f32x4*)&p0[4 * (j ^ (lane & 7))] = u0;
      *(f32x4*)&p1[4 * (j ^ (lane & 7))] = u1;
    }
    if (hi == 0) {
      CBl[256 + (qt * 2 + 0) * 32 + l31] = lt0;
      CBl[256 + (qt * 2 + 1) * 32 + l31] = lt1;
    }
  }
  __syncthreads();
  if (!subw && !ks) {
    const float* p0 = CB + (size_t)((qt * 2 + 0) * 64 + lane) * 32;
    const float* p1 = CB + (size_t)((qt * 2 + 1) * 64 + lane) * 32;
#pragma unroll
    for (int j = 0; j < 8; j++) {
      f32x4 u0 = *(const f32x4*)&p0[4 * (j ^ (lane & 7))];
      f32x4 u1 = *(const f32x4*)&p1[4 * (j ^ (lane & 7))];
#pragma unroll
      for (int e = 0; e < 4; e++) {
        if (j < 4) { acc00[4 * j + e] += u0[e]; acc10[4 * j + e] += u1[e]; }
        else       { acc01[4 * (j - 4) + e] += u0[e]; acc11[4 * (j - 4) + e] += u1[e]; }
      }
    }
    lt0 += CBl[256 + (qt * 2 + 0) * 32 + l31];
    lt1 += CBl[256 + (qt * 2 + 1) * 32 + l31];
    float inv0 = 1.0f / lt0;
    float inv1 = 1.0f / lt1;
#pragma unroll
    for (int qb = 0; qb < 2; qb++) {
      float inv = qb ? inv1 : inv0;
      u16* Ts = (u16*)((char*)lds + (qt * 2 + qb) * 8192);  // 32 q x 64 d, chunk-XOR swizzled
#pragma unroll
      for (int dt = 0; dt < 2; dt++)
#pragma unroll
        for (int r2 = 0; r2 < 4; r2++) {
          u16x4 o;
#pragma unroll
          for (int e = 0; e < 4; e++) {
            float v;
            if (qb == 0) v = dt ? acc01[4 * r2 + e] : acc00[4 * r2 + e];
            else         v = dt ? acc11[4 * r2 + e] : acc10[4 * r2 + e];
            o[e] = f2bf(v * inv);
          }
          int dbase = dt * 32 + r2 * 8 + hi * 4;
          int byteoff = l31 * 128 + ((dbase * 2) ^ (sw << 4));
          *(u16x4*)((char*)Ts + byteoff) = o;
        }
#pragma unroll
      for (int p4 = 0; p4 < 4; p4++) {
        int row = p4 * 8 + (lane >> 3);
        int c16 = lane & 7;
        u16x8 v = *(const u16x8*)((const char*)Ts + row * 128 + ((c16 << 4) ^ ((row & 7) << 4)));
        *(u16x8*)&Y[((size_t)(b * T + q0 + qt * 64 + qb * 32 + row)) * 1024 + h * 64 + c16 * 8] = v;
      }
    }
  }
}

extern "C" void kernel_launch(void* const* d_in, const int* in_sizes, int n_in,
                              void* d_out, int out_size, void* d_ws, size_t ws_size,
                              hipStream_t stream) {
  const float* q = (const float*)d_in[0];
  const float* k_xl = (const float*)d_in[1];
  const float* v_xl = (const float*)d_in[2];
  const float* W_qkv = (const float*)d_in[3];
  const float* W_proj = (const float*)d_in[4];
  const float* pos = (const float*)d_in[5];

  u16* wqkv = (u16*)d_ws;                       // 3072*1024
  u16* wproj = wqkv + (size_t)3072 * 1024;      // 1024*1024
  u16* qbf = wproj + (size_t)1024 * 1024;       // 4096*1024
  u16* qkvb = qbf + (size_t)4096 * 1024;        // 4096*3072
  u16* khxl = qkvb + (size_t)4096 * 3072;       // 32*2048*64
  u16* vt = khxl + (size_t)4 * 1024 * 1024;     // 32*64*4096
  u16* ybf = vt + (size_t)8 * 1024 * 1024;      // 4096*1024

  const float SC = 0.125f * 1.4426950408889634f;  // 1/sqrt(64) * log2(e)

  cvt_fuse<<<10240, 256, 0, stream>>>(q, W_qkv, W_proj, k_xl, pos, qbf, wqkv, wproj, khxl, SC);

  gemm_bt3<1><<<dim3(24, 32), 256, 0, stream>>>(qbf, wqkv, qkvb, 4096, 3072, 1024);

  build_vt<<<dim3(64, 32), 256, 0, stream>>>(v_xl, qkvb, vt);

  attn_fwd12<<<dim3(16, 32), 512, 0, stream>>>(qkvb, khxl, vt, ybf);

  gemm_bt3<0><<<dim3(8, 32), 256, 0, stream>>>(ybf, wproj, d_out, 4096, 1024, 1024);
}

// Round 13
// 178.996 us; speedup vs baseline: 4.1836x; 4.1836x over previous
//
#include <hip/hip_runtime.h>

typedef unsigned short u16;
typedef unsigned int u32;
typedef u16 u16x4 __attribute__((ext_vector_type(4)));
typedef u16 u16x8 __attribute__((ext_vector_type(8)));
typedef __bf16 bf16x8 __attribute__((ext_vector_type(8)));
typedef float f32x4 __attribute__((ext_vector_type(4)));
typedef float f32x16 __attribute__((ext_vector_type(16)));

static __device__ __forceinline__ u16 f2bf(float f) {
  union { float f; u32 u; } x; x.f = f;
  u32 r = x.u + 0x7fffu + ((x.u >> 16) & 1u);
  return (u16)(r >> 16);
}
static __device__ __forceinline__ u32 packbf(float a, float b) {
  union { u32 u; __bf16 h[2]; } x; x.h[0] = (__bf16)a; x.h[1] = (__bf16)b; return x.u;
}
static __device__ __forceinline__ void pl32swap(u32& a, u32& b) {
  asm volatile("v_permlane32_swap_b32 %0, %1" : "+v"(a), "+v"(b));
}
static __device__ __forceinline__ void gload16(const void* g, void* l) {
  __builtin_amdgcn_global_load_lds((const __attribute__((address_space(1))) unsigned int*)g,
                                   (__attribute__((address_space(3))) unsigned int*)l, 16, 0, 0);
}

// ---------------- fused fp32->bf16 casts + K_xl(+pos) build ----------------
__global__ __launch_bounds__(256) void cvt_fuse(const float* __restrict__ q, const float* __restrict__ wqkv_f,
                                                const float* __restrict__ wproj_f, const float* __restrict__ k_xl,
                                                const float* __restrict__ pos, u16* __restrict__ qbf,
                                                u16* __restrict__ wqkv, u16* __restrict__ wproj,
                                                u16* __restrict__ khxl, float sc) {
  int i = blockIdx.x * 256 + threadIdx.x;
  if (i < 2097152) {
    const float* src;
    u16* dst;
    int j;
    float s = 1.0f;
    if (i < 1048576) { src = q; dst = qbf; j = i; }
    else if (i < 1835008) { j = i - 1048576; src = wqkv_f; dst = wqkv; if (j < 262144) s = sc; }
    else { j = i - 1835008; src = wproj_f; dst = wproj; }
    float4 v = reinterpret_cast<const float4*>(src)[j];
    u16x4 o; o[0] = f2bf(v.x * s); o[1] = f2bf(v.y * s); o[2] = f2bf(v.z * s); o[3] = f2bf(v.w * s);
    reinterpret_cast<u16x4*>(dst)[j] = o;
  } else {
    int idx = i - 2097152;
    int d8 = idx & 7;
    int s = (idx >> 3) & 2047;
    int bh = idx >> 14;
    int b = bh >> 4, h = bh & 15;
    size_t src = ((size_t)(b * 2048 + s)) * 1024 + h * 64 + d8 * 8;
    size_t ps = ((size_t)s) * 1024 + h * 64 + d8 * 8;
    float4 a0 = *(const float4*)&k_xl[src];
    float4 a1 = *(const float4*)&k_xl[src + 4];
    float4 p0 = *(const float4*)&pos[ps];
    float4 p1 = *(const float4*)&pos[ps + 4];
    u16x8 o;
    o[0] = f2bf(a0.x + p0.x); o[1] = f2bf(a0.y + p0.y); o[2] = f2bf(a0.z + p0.z); o[3] = f2bf(a0.w + p0.w);
    o[4] = f2bf(a1.x + p1.x); o[5] = f2bf(a1.y + p1.y); o[6] = f2bf(a1.z + p1.z); o[7] = f2bf(a1.w + p1.w);
    *(u16x8*)&khxl[((size_t)bh * 2048 + s) * 64 + d8 * 8] = o;
  }
}

// ---------------- GEMM: 2-phase dbuf pipeline, BK=64, gload_lds + XOR swizzle ----------------
template <int OUT_BF16>
__global__ __launch_bounds__(256, 2) void gemm_bt3(const u16* __restrict__ A, const u16* __restrict__ B,
                                                   void* __restrict__ Cout, int M, int N, int K) {
  __shared__ alignas(128) u16 As[2][8192];
  __shared__ alignas(128) u16 Bs[2][8192];
  const int tid = threadIdx.x;
  const int m0 = blockIdx.y * 128, n0 = blockIdx.x * 128;
  const int wid = tid >> 6, lane = tid & 63;
  const int lm = lane & 15, lg = lane >> 4;
  const int wm = (wid >> 1) * 64, wn = (wid & 1) * 64;
  int srow[4], scol[4], dsto[4];
#pragma unroll
  for (int i = 0; i < 4; i++) {
    int li = tid + i * 256;
    srow[i] = li >> 3;
    scol[i] = ((li & 7) ^ (srow[i] & 7)) * 8;
    dsto[i] = (i * 256 + wid * 64) * 8;
  }
  f32x4 acc[4][4] = {};
#pragma unroll
  for (int i = 0; i < 4; i++) {
    gload16(&A[(size_t)(m0 + srow[i]) * K + scol[i]], &As[0][dsto[i]]);
    gload16(&B[(size_t)(n0 + srow[i]) * K + scol[i]], &Bs[0][dsto[i]]);
  }
  int cur = 0;
  for (int k0 = 0; k0 < K; k0 += 64) {
    __syncthreads();
    if (k0 + 64 < K) {
#pragma unroll
      for (int i = 0; i < 4; i++) {
        gload16(&A[(size_t)(m0 + srow[i]) * K + k0 + 64 + scol[i]], &As[cur ^ 1][dsto[i]]);
        gload16(&B[(size_t)(n0 + srow[i]) * K + k0 + 64 + scol[i]], &Bs[cur ^ 1][dsto[i]]);
      }
    }
    const u16* Asb = As[cur];
    const u16* Bsb = Bs[cur];
#pragma unroll
    for (int ks = 0; ks < 2; ks++) {
      bf16x8 af[4], bfr[4];
#pragma unroll
      for (int mi = 0; mi < 4; mi++) {
        int row = wm + mi * 16 + lm;
        af[mi] = *(const bf16x8*)&Asb[row * 64 + (((ks * 4 + lg) ^ (row & 7)) << 3)];
      }
#pragma unroll
      for (int ni = 0; ni < 4; ni++) {
        int row = wn + ni * 16 + lm;
        bfr[ni] = *(const bf16x8*)&Bsb[row * 64 + (((ks * 4 + lg) ^ (row & 7)) << 3)];
      }
#pragma unroll
      for (int mi = 0; mi < 4; mi++)
#pragma unroll
        for (int ni = 0; ni < 4; ni++)
          acc[mi][ni] = __builtin_amdgcn_mfma_f32_16x16x32_bf16(af[mi], bfr[ni], acc[mi][ni], 0, 0, 0);
    }
    cur ^= 1;
  }
#pragma unroll
  for (int mi = 0; mi < 4; mi++)
#pragma unroll
    for (int ni = 0; ni < 4; ni++)
#pragma unroll
      for (int r = 0; r < 4; r++) {
        int row = m0 + wm + mi * 16 + lg * 4 + r;
        int col = n0 + wn + ni * 16 + lm;
        if (OUT_BF16) ((u16*)Cout)[(size_t)row * N + col] = f2bf(acc[mi][ni][r]);
        else          ((float*)Cout)[(size_t)row * N + col] = acc[mi][ni][r];
      }
}

// ---------------- Vt[b][h][d][s] (transposed V) ----------------
__global__ __launch_bounds__(256) void build_vt(const float* __restrict__ v_xl, const u16* __restrict__ qkvb,
                                                u16* __restrict__ Vt) {
  __shared__ u16 tile[64][72];
  const int bh = blockIdx.y, b = bh >> 4, h = bh & 15;
  const int s0 = blockIdx.x * 64;
  const int tid = threadIdx.x;
  {
    int sl = tid >> 2;
    int dseg = (tid & 3) * 16;
    if (s0 < 2048) {
      const float* src = v_xl + ((size_t)(b * 2048 + s0 + sl)) * 1024 + h * 64 + dseg;
#pragma unroll
      for (int j = 0; j < 16; j += 4) {
        float4 v = *(const float4*)&src[j];
        tile[sl][dseg + j] = f2bf(v.x);
        tile[sl][dseg + j + 1] = f2bf(v.y);
        tile[sl][dseg + j + 2] = f2bf(v.z);
        tile[sl][dseg + j + 3] = f2bf(v.w);
      }
    } else {
      const u16* src = qkvb + ((size_t)(b * 2048 + s0 - 2048 + sl)) * 3072 + 2048 + h * 64 + dseg;
      *(u16x8*)&tile[sl][dseg] = *(const u16x8*)&src[0];
      *(u16x8*)&tile[sl][dseg + 8] = *(const u16x8*)&src[8];
    }
  }
  __syncthreads();
  {
    int d = tid >> 2;
    int sseg = (tid & 3) * 16;
    u16* dst = Vt + ((size_t)bh * 64 + d) * 4096 + s0 + sseg;
    u16x8 o0, o1;
#pragma unroll
    for (int j = 0; j < 8; j++) { o0[j] = tile[sseg + j][d]; o1[j] = tile[sseg + 8 + j][d]; }
    *(u16x8*)&dst[0] = o0;
    *(u16x8*)&dst[8] = o1;
  }
}

// ---------------- flash attention v13: R12 structure, spill-fixed launch bounds ----------------
// grid (T/128, B*H) XCD-swizzled; 512 thr, 8 waves (qt, ks, subw). Wave = 64 q (2 q-blocks) x keys
// [subw*64+ks*32, +32) of each 128-key tile. launch_bounds(512,2): VGPR cap 256 -> no spill
// (R12's (512,4) clamped VGPR to 64 and spilled 3GB to scratch).
__global__ __launch_bounds__(512, 2) void attn_fwd13(const u16* __restrict__ qkvb, const u16* __restrict__ khxl,
                                                     const u16* __restrict__ vt, u16* __restrict__ Y) {
  const int T = 2048;
  __shared__ alignas(128) u16 lds[32768];  // u16 idx: KA=0 KB=8192 VA=16384 VB=24576 (64KB)
  __shared__ float CBl[384];
  const int dd = blockIdx.x + (blockIdx.y << 4);  // [0,512)
  const int w = ((dd & 7) << 6) + (dd >> 3);      // bijective XCD-chunked swizzle
  const int bh = w >> 4;
  const int q0 = (w & 15) * 128;
  const int tid = threadIdx.x, wid = tid >> 6, lane = tid & 63;
  const int qt = wid >> 2, ks = (wid >> 1) & 1, subw = wid & 1;
  const int l31 = lane & 31, hi = lane >> 5;
  const int sw = l31 & 7;
  const int b = bh >> 4, h = bh & 15;
  // Q fragments for both q-blocks (scale*log2e folded into W_qkv Q-rows)
  bf16x8 qf0[4], qf1[4];
  {
    const u16* Qp0 = qkvb + (size_t)(b * T + q0 + qt * 64 + l31) * 3072 + h * 64;
    const u16* Qp1 = Qp0 + (size_t)32 * 3072;
#pragma unroll
    for (int c = 0; c < 4; c++) {
      qf0[c] = *(const bf16x8*)&Qp0[c * 16 + hi * 8];
      qf1[c] = *(const bf16x8*)&Qp1[c * 16 + hi * 8];
    }
  }
  // staging (exact R8): 512 threads, srow in [0,64); 2 K-chunks + 2 V-chunks per thread per tile
  const int srow = tid >> 3, pc = tid & 7;
  const int scol = (pc ^ (srow & 7)) * 8;
  const u16* kxl_s = khxl + ((size_t)bh * 2048 + srow) * 64 + scol;                 // +4096: rows+64; tile +8192
  const u16* knew_s = qkvb + (size_t)(b * T + srow) * 3072 + 1024 + h * 64 + scol;  // +196608: rows+64; tile +393216
  const u16* v_s = vt + ((size_t)bh * 64 + srow) * 4096 + scol;                     // +64: keys+64; tile +128
  const int kd = tid * 8;
  f32x16 acc00 = {0.0f}, acc01 = {0.0f}, acc10 = {0.0f}, acc11 = {0.0f};
  float lrun0 = 0.0f, lrun1 = 0.0f;
  const int krow = subw * 64 + ks * 32 + l31;

#define STAGE_XL(KO, VO)                              \
  do {                                                \
    gload16(kxl_s, &lds[(KO) + kd]);                  \
    gload16(kxl_s + 4096, &lds[(KO) + 4096 + kd]);    \
    gload16(v_s, &lds[(VO) + kd]);                    \
    gload16(v_s + 64, &lds[(VO) + 4096 + kd]);        \
    kxl_s += 8192; v_s += 128;                        \
  } while (0)
#define STAGE_NEW(KO, VO)                             \
  do {                                                \
    gload16(knew_s, &lds[(KO) + kd]);                 \
    gload16(knew_s + 196608, &lds[(KO) + 4096 + kd]); \
    gload16(v_s, &lds[(VO) + kd]);                    \
    gload16(v_s + 64, &lds[(VO) + 4096 + kd]);        \
    knew_s += 393216; v_s += 128;                     \
  } while (0)
#define COMPUTE(KO, VO)                                                             \
  do {                                                                              \
    const int _vo = (VO) + subw * 4096;                                             \
    bf16x8 kf0 = *(const bf16x8*)&lds[(KO) + krow * 64 + (((0 + hi) ^ sw) << 3)];   \
    bf16x8 kf1 = *(const bf16x8*)&lds[(KO) + krow * 64 + (((2 + hi) ^ sw) << 3)];   \
    bf16x8 kf2 = *(const bf16x8*)&lds[(KO) + krow * 64 + (((4 + hi) ^ sw) << 3)];   \
    bf16x8 kf3 = *(const bf16x8*)&lds[(KO) + krow * 64 + (((6 + hi) ^ sw) << 3)];   \
    f32x16 s0 = {0.0f}, s1 = {0.0f};                                                \
    __builtin_amdgcn_s_setprio(1);                                                  \
    s0 = __builtin_amdgcn_mfma_f32_32x32x16_bf16(kf0, qf0[0], s0, 0, 0, 0);         \
    s1 = __builtin_amdgcn_mfma_f32_32x32x16_bf16(kf0, qf1[0], s1, 0, 0, 0);         \
    s0 = __builtin_amdgcn_mfma_f32_32x32x16_bf16(kf1, qf0[1], s0, 0, 0, 0);         \
    s1 = __builtin_amdgcn_mfma_f32_32x32x16_bf16(kf1, qf1[1], s1, 0, 0, 0);         \
    s0 = __builtin_amdgcn_mfma_f32_32x32x16_bf16(kf2, qf0[2], s0, 0, 0, 0);         \
    s1 = __builtin_amdgcn_mfma_f32_32x32x16_bf16(kf2, qf1[2], s1, 0, 0, 0);         \
    s0 = __builtin_amdgcn_mfma_f32_32x32x16_bf16(kf3, qf0[3], s0, 0, 0, 0);         \
    s1 = __builtin_amdgcn_mfma_f32_32x32x16_bf16(kf3, qf1[3], s1, 0, 0, 0);         \
    __builtin_amdgcn_s_setprio(0);                                                  \
    u32 w40[4][2], w41[4][2];                                                       \
    _Pragma("unroll")                                                               \
    for (int r = 0; r < 16; r++) s0[r] = __builtin_amdgcn_exp2f(s0[r]);             \
    lrun0 += (((s0[0] + s0[1]) + (s0[2] + s0[3])) + ((s0[4] + s0[5]) + (s0[6] + s0[7])))         \
           + (((s0[8] + s0[9]) + (s0[10] + s0[11])) + ((s0[12] + s0[13]) + (s0[14] + s0[15])));  \
    _Pragma("unroll")                                                               \
    for (int g = 0; g < 4; g++) {                                                   \
      w40[g][0] = packbf(s0[4 * g + 0], s0[4 * g + 1]);                             \
      w40[g][1] = packbf(s0[4 * g + 2], s0[4 * g + 3]);                             \
    }                                                                               \
    _Pragma("unroll")                                                               \
    for (int r = 0; r < 16; r++) s1[r] = __builtin_amdgcn_exp2f(s1[r]);             \
    lrun1 += (((s1[0] + s1[1]) + (s1[2] + s1[3])) + ((s1[4] + s1[5]) + (s1[6] + s1[7])))         \
           + (((s1[8] + s1[9]) + (s1[10] + s1[11])) + ((s1[12] + s1[13]) + (s1[14] + s1[15])));  \
    _Pragma("unroll")                                                               \
    for (int g = 0; g < 4; g++) {                                                   \
      w41[g][0] = packbf(s1[4 * g + 0], s1[4 * g + 1]);                             \
      w41[g][1] = packbf(s1[4 * g + 2], s1[4 * g + 3]);                             \
    }                                                                               \
    __builtin_amdgcn_s_setprio(1);                                                  \
    _Pragma("unroll")                                                               \
    for (int m2 = 0; m2 < 2; m2++) {                                                \
      int cg = 2 * (ks * 2 + m2) + hi;                                              \
      bf16x8 v0 = *(const bf16x8*)&lds[_vo + l31 * 64 + ((cg ^ sw) << 3)];          \
      bf16x8 v1 = *(const bf16x8*)&lds[_vo + (32 + l31) * 64 + ((cg ^ sw) << 3)];   \
      u32 A0 = w40[2 * m2][0], A2 = w40[2 * m2 + 1][0];                             \
      pl32swap(A0, A2);                                                             \
      u32 A1 = w40[2 * m2][1], A3 = w40[2 * m2 + 1][1];                             \
      pl32swap(A1, A3);                                                             \
      union { u32 u[4]; bf16x8 v; } pf0;                                            \
      pf0.u[0] = A0; pf0.u[1] = A1; pf0.u[2] = A2; pf0.u[3] = A3;                   \
      acc00 = __builtin_amdgcn_mfma_f32_32x32x16_bf16(v0, pf0.v, acc00, 0, 0, 0);   \
      acc01 = __builtin_amdgcn_mfma_f32_32x32x16_bf16(v1, pf0.v, acc01, 0, 0, 0);   \
      u32 B0 = w41[2 * m2][0], B2 = w41[2 * m2 + 1][0];                             \
      pl32swap(B0, B2);                                                             \
      u32 B1 = w41[2 * m2][1], B3 = w41[2 * m2 + 1][1];                             \
      pl32swap(B1, B3);                                                             \
      union { u32 u[4]; bf16x8 v; } pf1;                                            \
      pf1.u[0] = B0; pf1.u[1] = B1; pf1.u[2] = B2; pf1.u[3] = B3;                   \
      acc10 = __builtin_amdgcn_mfma_f32_32x32x16_bf16(v0, pf1.v, acc10, 0, 0, 0);   \
      acc11 = __builtin_amdgcn_mfma_f32_32x32x16_bf16(v1, pf1.v, acc11, 0, 0, 0);   \
    }                                                                               \
    __builtin_amdgcn_s_setprio(0);                                                  \
  } while (0)

  // 16 XL tiles of 128 keys, then 16 NEW tiles (exact R8 schedule)
  STAGE_XL(0, 16384);
  for (int j = 0; j < 7; ++j) {
    __syncthreads();
    STAGE_XL(8192, 24576);
    COMPUTE(0, 16384);
    __syncthreads();
    STAGE_XL(0, 16384);
    COMPUTE(8192, 24576);
  }
  __syncthreads();
  STAGE_XL(8192, 24576);   // XL 15
  COMPUTE(0, 16384);       // XL 14
  __syncthreads();
  STAGE_NEW(0, 16384);     // NEW 0
  COMPUTE(8192, 24576);    // XL 15
  for (int j = 0; j < 7; ++j) {
    __syncthreads();
    STAGE_NEW(8192, 24576);
    COMPUTE(0, 16384);
    __syncthreads();
    STAGE_NEW(0, 16384);
    COMPUTE(8192, 24576);
  }
  __syncthreads();
  STAGE_NEW(8192, 24576);  // NEW 15
  COMPUTE(0, 16384);       // NEW 14
  __syncthreads();
  COMPUTE(8192, 24576);    // NEW 15
#undef STAGE_XL
#undef STAGE_NEW
#undef COMPUTE

  // ---- 2-step combine of 4 partials per q-group, then normalize + transpose + store ----
  float lt0 = lrun0 + __shfl_xor(lrun0, 32);
  float lt1 = lrun1 + __shfl_xor(lrun1, 32);
  __syncthreads();
  float* CB = (float*)lds;  // step1: 8 groups x 64 lanes x 32 f32 = 64 KB
  // step 1: subw=1 publish -> subw=0 absorb (groups keyed by (qt,qb,ks))
  if (subw) {
    float* p0 = CB + (size_t)(((qt * 2 + 0) * 2 + ks) * 64 + lane) * 32;
    float* p1 = CB + (size_t)(((qt * 2 + 1) * 2 + ks) * 64 + lane) * 32;
#pragma unroll
    for (int j = 0; j < 8; j++) {
      f32x4 u0, u1;
#pragma unroll
      for (int e = 0; e < 4; e++) {
        u0[e] = (j < 4) ? acc00[4 * j + e] : acc01[4 * (j - 4) + e];
        u1[e] = (j < 4) ? acc10[4 * j + e] : acc11[4 * (j - 4) + e];
      }
      *(f32x4*)&p0[4 * (j ^ (lane & 7))] = u0;
      *(f32x4*)&p1[4 * (j ^ (lane & 7))] = u1;
    }
    if (hi == 0) {
      CBl[((qt * 2 + 0) * 2 + ks) * 32 + l31] = lt0;
      CBl[((qt * 2 + 1) * 2 + ks) * 32 + l31] = lt1;
    }
  }
  __syncthreads();
  if (!subw) {
    const float* p0 = CB + (size_t)(((qt * 2 + 0) * 2 + ks) * 64 + lane) * 32;
    const float* p1 = CB + (size_t)(((qt * 2 + 1) * 2 + ks) * 64 + lane) * 32;
#pragma unroll
    for (int j = 0; j < 8; j++) {
      f32x4 u0 = *(const f32x4*)&p0[4 * (j ^ (lane & 7))];
      f32x4 u1 = *(const f32x4*)&p1[4 * (j ^ (lane & 7))];
#pragma unroll
      for (int e = 0; e < 4; e++) {
        if (j < 4) { acc00[4 * j + e] += u0[e]; acc10[4 * j + e] += u1[e]; }
        else       { acc01[4 * (j - 4) + e] += u0[e]; acc11[4 * (j - 4) + e] += u1[e]; }
      }
    }
    lt0 += CBl[((qt * 2 + 0) * 2 + ks) * 32 + l31];
    lt1 += CBl[((qt * 2 + 1) * 2 + ks) * 32 + l31];
  }
  __syncthreads();
  // step 2: ks=1 (subw=0) publish -> ks=0 absorb (groups keyed by (qt,qb))
  if (!subw && ks) {
    float* p0 = CB + (size_t)((qt * 2 + 0) * 64 + lane) * 32;
    float* p1 = CB + (size_t)((qt * 2 + 1) * 64 + lane) * 32;
#pragma unroll
    for (int j = 0; j < 8; j++) {
      f32x4 u0, u1;
#pragma unroll
      for (int e = 0; e < 4; e++) {
        u0[e] = (j < 4) ? acc00[4 * j + e] : acc01[4 * (j - 4) + e];
        u1[e] = (j < 4) ? acc10[4 * j + e] : acc11[4 * (j - 4) + e];
      }
      *(f32x4*)&p0[4 * (j ^ (lane & 7))] = u0;
      *(f32x4*)&p1[4 * (j ^ (lane & 7))] = u1;
    }
    if (hi == 0) {
      CBl[256 + (qt * 2 + 0) * 32 + l31] = lt0;
      CBl[256 + (qt * 2 + 1) * 32 + l31] = lt1;
    }
  }
  __syncthreads();
  if (!subw && !ks) {
    const float* p0 = CB + (size_t)((qt * 2 + 0) * 64 + lane) * 32;
    const float* p1 = CB + (size_t)((qt * 2 + 1) * 64 + lane) * 32;
#pragma unroll
    for (int j = 0; j < 8; j++) {
      f32x4 u0 = *(const f32x4*)&p0[4 * (j ^ (lane & 7))];
      f32x4 u1 = *(const f32x4*)&p1[4 * (j ^ (lane & 7))];
#pragma unroll
      for (int e = 0; e < 4; e++) {
        if (j < 4) { acc00[4 * j + e] += u0[e]; acc10[4 * j + e] += u1[e]; }
        else       { acc01[4 * (j - 4) + e] += u0[e]; acc11[4 * (j - 4) + e] += u1[e]; }
      }
    }
    lt0 += CBl[256 + (qt * 2 + 0) * 32 + l31];
    lt1 += CBl[256 + (qt * 2 + 1) * 32 + l31];
    float inv0 = 1.0f / lt0;
    float inv1 = 1.0f / lt1;
#pragma unroll
    for (int qb = 0; qb < 2; qb++) {
      float inv = qb ? inv1 : inv0;
      u16* Ts = (u16*)((char*)lds + (qt * 2 + qb) * 8192);  // 32 q x 64 d, chunk-XOR swizzled
#pragma unroll
      for (int dt = 0; dt < 2; dt++)
#pragma unroll
        for (int r2 = 0; r2 < 4; r2++) {
          u16x4 o;
#pragma unroll
          for (int e = 0; e < 4; e++) {
            float v;
            if (qb == 0) v = dt ? acc01[4 * r2 + e] : acc00[4 * r2 + e];
            else         v = dt ? acc11[4 * r2 + e] : acc10[4 * r2 + e];
            o[e] = f2bf(v * inv);
          }
          int dbase = dt * 32 + r2 * 8 + hi * 4;
          int byteoff = l31 * 128 + ((dbase * 2) ^ (sw << 4));
          *(u16x4*)((char*)Ts + byteoff) = o;
        }
#pragma unroll
      for (int p4 = 0; p4 < 4; p4++) {
        int row = p4 * 8 + (lane >> 3);
        int c16 = lane & 7;
        u16x8 v = *(const u16x8*)((const char*)Ts + row * 128 + ((c16 << 4) ^ ((row & 7) << 4)));
        *(u16x8*)&Y[((size_t)(b * T + q0 + qt * 64 + qb * 32 + row)) * 1024 + h * 64 + c16 * 8] = v;
      }
    }
  }
}

extern "C" void kernel_launch(void* const* d_in, const int* in_sizes, int n_in,
                              void* d_out, int out_size, void* d_ws, size_t ws_size,
                              hipStream_t stream) {
  const float* q = (const float*)d_in[0];
  const float* k_xl = (const float*)d_in[1];
  const float* v_xl = (const float*)d_in[2];
  const float* W_qkv = (const float*)d_in[3];
  const float* W_proj = (const float*)d_in[4];
  const float* pos = (const float*)d_in[5];

  u16* wqkv = (u16*)d_ws;                       // 3072*1024
  u16* wproj = wqkv + (size_t)3072 * 1024;      // 1024*1024
  u16* qbf = wproj + (size_t)1024 * 1024;       // 4096*1024
  u16* qkvb = qbf + (size_t)4096 * 1024;        // 4096*3072
  u16* khxl = qkvb + (size_t)4096 * 3072;       // 32*2048*64
  u16* vt = khxl + (size_t)4 * 1024 * 1024;     // 32*64*4096
  u16* ybf = vt + (size_t)8 * 1024 * 1024;      // 4096*1024

  const float SC = 0.125f * 1.4426950408889634f;  // 1/sqrt(64) * log2(e)

  cvt_fuse<<<10240, 256, 0, stream>>>(q, W_qkv, W_proj, k_xl, pos, qbf, wqkv, wproj, khxl, SC);

  gemm_bt3<1><<<dim3(24, 32), 256, 0, stream>>>(qbf, wqkv, qkvb, 4096, 3072, 1024);

  build_vt<<<dim3(64, 32), 256, 0, stream>>>(v_xl, qkvb, vt);

  attn_fwd13<<<dim3(16, 32), 512, 0, stream>>>(qkvb, khxl, vt, ybf);

  gemm_bt3<0><<<dim3(8, 32), 256, 0, stream>>>(ybf, wproj, d_out, 4096, 1024, 1024);
}

// Round 14
// 164.183 us; speedup vs baseline: 4.5611x; 1.0902x over previous
//
#include <hip/hip_runtime.h>

typedef unsigned short u16;
typedef unsigned int u32;
typedef u16 u16x4 __attribute__((ext_vector_type(4)));
typedef u16 u16x8 __attribute__((ext_vector_type(8)));
typedef __bf16 bf16x8 __attribute__((ext_vector_type(8)));
typedef float f32x4 __attribute__((ext_vector_type(4)));
typedef float f32x16 __attribute__((ext_vector_type(16)));

static __device__ __forceinline__ u16 f2bf(float f) {
  union { float f; u32 u; } x; x.f = f;
  u32 r = x.u + 0x7fffu + ((x.u >> 16) & 1u);
  return (u16)(r >> 16);
}
static __device__ __forceinline__ u32 packbf(float a, float b) {
  union { u32 u; __bf16 h[2]; } x; x.h[0] = (__bf16)a; x.h[1] = (__bf16)b; return x.u;
}
static __device__ __forceinline__ void pl32swap(u32& a, u32& b) {
  asm volatile("v_permlane32_swap_b32 %0, %1" : "+v"(a), "+v"(b));
}
static __device__ __forceinline__ void gload16(const void* g, void* l) {
  __builtin_amdgcn_global_load_lds((const __attribute__((address_space(1))) unsigned int*)g,
                                   (__attribute__((address_space(3))) unsigned int*)l, 16, 0, 0);
}

// ---------------- fused fp32->bf16 casts + K_xl(+pos) build ----------------
__global__ __launch_bounds__(256) void cvt_fuse(const float* __restrict__ q, const float* __restrict__ wqkv_f,
                                                const float* __restrict__ wproj_f, const float* __restrict__ k_xl,
                                                const float* __restrict__ pos, u16* __restrict__ qbf,
                                                u16* __restrict__ wqkv, u16* __restrict__ wproj,
                                                u16* __restrict__ khxl, float sc) {
  int i = blockIdx.x * 256 + threadIdx.x;
  if (i < 2097152) {
    const float* src;
    u16* dst;
    int j;
    float s = 1.0f;
    if (i < 1048576) { src = q; dst = qbf; j = i; }
    else if (i < 1835008) { j = i - 1048576; src = wqkv_f; dst = wqkv; if (j < 262144) s = sc; }
    else { j = i - 1835008; src = wproj_f; dst = wproj; }
    float4 v = reinterpret_cast<const float4*>(src)[j];
    u16x4 o; o[0] = f2bf(v.x * s); o[1] = f2bf(v.y * s); o[2] = f2bf(v.z * s); o[3] = f2bf(v.w * s);
    reinterpret_cast<u16x4*>(dst)[j] = o;
  } else {
    int idx = i - 2097152;
    int d8 = idx & 7;
    int s = (idx >> 3) & 2047;
    int bh = idx >> 14;
    int b = bh >> 4, h = bh & 15;
    size_t src = ((size_t)(b * 2048 + s)) * 1024 + h * 64 + d8 * 8;
    size_t ps = ((size_t)s) * 1024 + h * 64 + d8 * 8;
    float4 a0 = *(const float4*)&k_xl[src];
    float4 a1 = *(const float4*)&k_xl[src + 4];
    float4 p0 = *(const float4*)&pos[ps];
    float4 p1 = *(const float4*)&pos[ps + 4];
    u16x8 o;
    o[0] = f2bf(a0.x + p0.x); o[1] = f2bf(a0.y + p0.y); o[2] = f2bf(a0.z + p0.z); o[3] = f2bf(a0.w + p0.w);
    o[4] = f2bf(a1.x + p1.x); o[5] = f2bf(a1.y + p1.y); o[6] = f2bf(a1.z + p1.z); o[7] = f2bf(a1.w + p1.w);
    *(u16x8*)&khxl[((size_t)bh * 2048 + s) * 64 + d8 * 8] = o;
  }
}

// ---------------- GEMM: 2-phase dbuf pipeline, BK=64, gload_lds + XOR swizzle + XCD block swizzle ----------------
template <int OUT_BF16>
__global__ __launch_bounds__(256, 2) void gemm_bt4(const u16* __restrict__ A, const u16* __restrict__ B,
                                                   void* __restrict__ Cout, int M, int N, int K) {
  __shared__ alignas(128) u16 As[2][8192];
  __shared__ alignas(128) u16 Bs[2][8192];
  const int tid = threadIdx.x;
  // XCD-chunked swizzle: nwg%8==0 for all our grids (768, 256). Consecutive A-panels per XCD.
  const int nbx = gridDim.x;
  const int nwg = nbx * gridDim.y;
  const int id = blockIdx.x + blockIdx.y * nbx;
  const int swz = (id & 7) * (nwg >> 3) + (id >> 3);
  const int m0 = (swz / nbx) * 128, n0 = (swz % nbx) * 128;
  const int wid = tid >> 6, lane = tid & 63;
  const int lm = lane & 15, lg = lane >> 4;
  const int wm = (wid >> 1) * 64, wn = (wid & 1) * 64;
  int srow[4], scol[4], dsto[4];
#pragma unroll
  for (int i = 0; i < 4; i++) {
    int li = tid + i * 256;
    srow[i] = li >> 3;
    scol[i] = ((li & 7) ^ (srow[i] & 7)) * 8;
    dsto[i] = (i * 256 + wid * 64) * 8;
  }
  f32x4 acc[4][4] = {};
#pragma unroll
  for (int i = 0; i < 4; i++) {
    gload16(&A[(size_t)(m0 + srow[i]) * K + scol[i]], &As[0][dsto[i]]);
    gload16(&B[(size_t)(n0 + srow[i]) * K + scol[i]], &Bs[0][dsto[i]]);
  }
  int cur = 0;
  for (int k0 = 0; k0 < K; k0 += 64) {
    __syncthreads();
    if (k0 + 64 < K) {
#pragma unroll
      for (int i = 0; i < 4; i++) {
        gload16(&A[(size_t)(m0 + srow[i]) * K + k0 + 64 + scol[i]], &As[cur ^ 1][dsto[i]]);
        gload16(&B[(size_t)(n0 + srow[i]) * K + k0 + 64 + scol[i]], &Bs[cur ^ 1][dsto[i]]);
      }
    }
    const u16* Asb = As[cur];
    const u16* Bsb = Bs[cur];
#pragma unroll
    for (int ks = 0; ks < 2; ks++) {
      bf16x8 af[4], bfr[4];
#pragma unroll
      for (int mi = 0; mi < 4; mi++) {
        int row = wm + mi * 16 + lm;
        af[mi] = *(const bf16x8*)&Asb[row * 64 + (((ks * 4 + lg) ^ (row & 7)) << 3)];
      }
#pragma unroll
      for (int ni = 0; ni < 4; ni++) {
        int row = wn + ni * 16 + lm;
        bfr[ni] = *(const bf16x8*)&Bsb[row * 64 + (((ks * 4 + lg) ^ (row & 7)) << 3)];
      }
#pragma unroll
      for (int mi = 0; mi < 4; mi++)
#pragma unroll
        for (int ni = 0; ni < 4; ni++)
          acc[mi][ni] = __builtin_amdgcn_mfma_f32_16x16x32_bf16(af[mi], bfr[ni], acc[mi][ni], 0, 0, 0);
    }
    cur ^= 1;
  }
#pragma unroll
  for (int mi = 0; mi < 4; mi++)
#pragma unroll
    for (int ni = 0; ni < 4; ni++)
#pragma unroll
      for (int r = 0; r < 4; r++) {
        int row = m0 + wm + mi * 16 + lg * 4 + r;
        int col = n0 + wn + ni * 16 + lm;
        if (OUT_BF16) ((u16*)Cout)[(size_t)row * N + col] = f2bf(acc[mi][ni][r]);
        else          ((float*)Cout)[(size_t)row * N + col] = acc[mi][ni][r];
      }
}

// ---------------- Vt[b][h][d][s] (transposed V) ----------------
__global__ __launch_bounds__(256) void build_vt(const float* __restrict__ v_xl, const u16* __restrict__ qkvb,
                                                u16* __restrict__ Vt) {
  __shared__ u16 tile[64][72];
  const int bh = blockIdx.y, b = bh >> 4, h = bh & 15;
  const int s0 = blockIdx.x * 64;
  const int tid = threadIdx.x;
  {
    int sl = tid >> 2;
    int dseg = (tid & 3) * 16;
    if (s0 < 2048) {
      const float* src = v_xl + ((size_t)(b * 2048 + s0 + sl)) * 1024 + h * 64 + dseg;
#pragma unroll
      for (int j = 0; j < 16; j += 4) {
        float4 v = *(const float4*)&src[j];
        tile[sl][dseg + j] = f2bf(v.x);
        tile[sl][dseg + j + 1] = f2bf(v.y);
        tile[sl][dseg + j + 2] = f2bf(v.z);
        tile[sl][dseg + j + 3] = f2bf(v.w);
      }
    } else {
      const u16* src = qkvb + ((size_t)(b * 2048 + s0 - 2048 + sl)) * 3072 + 2048 + h * 64 + dseg;
      *(u16x8*)&tile[sl][dseg] = *(const u16x8*)&src[0];
      *(u16x8*)&tile[sl][dseg + 8] = *(const u16x8*)&src[8];
    }
  }
  __syncthreads();
  {
    int d = tid >> 2;
    int sseg = (tid & 3) * 16;
    u16* dst = Vt + ((size_t)bh * 64 + d) * 4096 + s0 + sseg;
    u16x8 o0, o1;
#pragma unroll
    for (int j = 0; j < 8; j++) { o0[j] = tile[sseg + j][d]; o1[j] = tile[sseg + 8 + j][d]; }
    *(u16x8*)&dst[0] = o0;
    *(u16x8*)&dst[8] = o1;
  }
}

// ---------------- flash attention (R10 verbatim): 64q waves, launch_bounds(256,2) ----------------
// grid (T/128, B*H) XCD-swizzled; 256 thr, 4 waves (qt x ks). Wave = 64 q (2 q-blocks) x ks-half
// of each 64-key tile; K/V fragments read once, used by both q-blocks.
__global__ __launch_bounds__(256, 2) void attn_fwd10(const u16* __restrict__ qkvb, const u16* __restrict__ khxl,
                                                     const u16* __restrict__ vt, u16* __restrict__ Y) {
  const int T = 2048;
  __shared__ alignas(128) u16 lds[16384];  // u16 idx: KA=0 KB=4096 VA=8192 VB=12288 (32KB)
  __shared__ float CBl[128];
  const int dd = blockIdx.x + (blockIdx.y << 4);  // [0,512)
  const int w = ((dd & 7) << 6) + (dd >> 3);      // bijective XCD-chunked swizzle
  const int bh = w >> 4;
  const int q0 = (w & 15) * 128;
  const int tid = threadIdx.x, wid = tid >> 6, lane = tid & 63;
  const int qt = wid >> 1, ks = wid & 1;
  const int l31 = lane & 31, hi = lane >> 5;
  const int sw = l31 & 7;
  const int b = bh >> 4, h = bh & 15;
  bf16x8 qf0[4], qf1[4];
  {
    const u16* Qp0 = qkvb + (size_t)(b * T + q0 + qt * 64 + l31) * 3072 + h * 64;
    const u16* Qp1 = Qp0 + (size_t)32 * 3072;
#pragma unroll
    for (int c = 0; c < 4; c++) {
      qf0[c] = *(const bf16x8*)&Qp0[c * 16 + hi * 8];
      qf1[c] = *(const bf16x8*)&Qp1[c * 16 + hi * 8];
    }
  }
  const int srow = tid >> 3, pc = tid & 7;
  const int scol = (pc ^ (srow & 7)) * 8;
  const u16* kxl_s = khxl + ((size_t)bh * 2048 + srow) * 64 + scol;
  const u16* knew_s = qkvb + (size_t)(b * T + srow) * 3072 + 1024 + h * 64 + scol;
  const u16* v_s = vt + ((size_t)bh * 64 + srow) * 4096 + scol;
  const int kd = tid * 8;
  f32x16 acc00 = {0.0f}, acc01 = {0.0f}, acc10 = {0.0f}, acc11 = {0.0f};
  float lrun0 = 0.0f, lrun1 = 0.0f;
  const int krow = ks * 32 + l31;

#define STAGE_XL(KO, VO)                              \
  do {                                                \
    gload16(kxl_s, &lds[(KO) + kd]);                  \
    gload16(kxl_s + 2048, &lds[(KO) + 2048 + kd]);    \
    gload16(v_s, &lds[(VO) + kd]);                    \
    gload16(v_s + 131072, &lds[(VO) + 2048 + kd]);    \
    kxl_s += 4096; v_s += 64;                         \
  } while (0)
#define STAGE_NEW(KO, VO)                             \
  do {                                                \
    gload16(knew_s, &lds[(KO) + kd]);                 \
    gload16(knew_s + 98304, &lds[(KO) + 2048 + kd]);  \
    gload16(v_s, &lds[(VO) + kd]);                    \
    gload16(v_s + 131072, &lds[(VO) + 2048 + kd]);    \
    knew_s += 196608; v_s += 64;                      \
  } while (0)
#define COMPUTE(KO, VO)                                                             \
  do {                                                                              \
    bf16x8 kf0 = *(const bf16x8*)&lds[(KO) + krow * 64 + (((0 + hi) ^ sw) << 3)];   \
    bf16x8 kf1 = *(const bf16x8*)&lds[(KO) + krow * 64 + (((2 + hi) ^ sw) << 3)];   \
    bf16x8 kf2 = *(const bf16x8*)&lds[(KO) + krow * 64 + (((4 + hi) ^ sw) << 3)];   \
    bf16x8 kf3 = *(const bf16x8*)&lds[(KO) + krow * 64 + (((6 + hi) ^ sw) << 3)];   \
    f32x16 s0 = {0.0f}, s1 = {0.0f};                                                \
    __builtin_amdgcn_s_setprio(1);                                                  \
    s0 = __builtin_amdgcn_mfma_f32_32x32x16_bf16(kf0, qf0[0], s0, 0, 0, 0);         \
    s1 = __builtin_amdgcn_mfma_f32_32x32x16_bf16(kf0, qf1[0], s1, 0, 0, 0);         \
    s0 = __builtin_amdgcn_mfma_f32_32x32x16_bf16(kf1, qf0[1], s0, 0, 0, 0);         \
    s1 = __builtin_amdgcn_mfma_f32_32x32x16_bf16(kf1, qf1[1], s1, 0, 0, 0);         \
    s0 = __builtin_amdgcn_mfma_f32_32x32x16_bf16(kf2, qf0[2], s0, 0, 0, 0);         \
    s1 = __builtin_amdgcn_mfma_f32_32x32x16_bf16(kf2, qf1[2], s1, 0, 0, 0);         \
    s0 = __builtin_amdgcn_mfma_f32_32x32x16_bf16(kf3, qf0[3], s0, 0, 0, 0);         \
    s1 = __builtin_amdgcn_mfma_f32_32x32x16_bf16(kf3, qf1[3], s1, 0, 0, 0);         \
    __builtin_amdgcn_s_setprio(0);                                                  \
    u32 w40[4][2], w41[4][2];                                                       \
    _Pragma("unroll")                                                               \
    for (int r = 0; r < 16; r++) s0[r] = __builtin_amdgcn_exp2f(s0[r]);             \
    lrun0 += (((s0[0] + s0[1]) + (s0[2] + s0[3])) + ((s0[4] + s0[5]) + (s0[6] + s0[7])))         \
           + (((s0[8] + s0[9]) + (s0[10] + s0[11])) + ((s0[12] + s0[13]) + (s0[14] + s0[15])));  \
    _Pragma("unroll")                                                               \
    for (int g = 0; g < 4; g++) {                                                   \
      w40[g][0] = packbf(s0[4 * g + 0], s0[4 * g + 1]);                             \
      w40[g][1] = packbf(s0[4 * g + 2], s0[4 * g + 3]);                             \
    }                                                                               \
    _Pragma("unroll")                                                               \
    for (int r = 0; r < 16; r++) s1[r] = __builtin_amdgcn_exp2f(s1[r]);             \
    lrun1 += (((s1[0] + s1[1]) + (s1[2] + s1[3])) + ((s1[4] + s1[5]) + (s1[6] + s1[7])))         \
           + (((s1[8] + s1[9]) + (s1[10] + s1[11])) + ((s1[12] + s1[13]) + (s1[14] + s1[15])));  \
    _Pragma("unroll")                                                               \
    for (int g = 0; g < 4; g++) {                                                   \
      w41[g][0] = packbf(s1[4 * g + 0], s1[4 * g + 1]);                             \
      w41[g][1] = packbf(s1[4 * g + 2], s1[4 * g + 3]);                             \
    }                                                                               \
    __builtin_amdgcn_s_setprio(1);                                                  \
    _Pragma("unroll")                                                               \
    for (int m2 = 0; m2 < 2; m2++) {                                                \
      int cg = 2 * (ks * 2 + m2) + hi;                                              \
      bf16x8 v0 = *(const bf16x8*)&lds[(VO) + l31 * 64 + ((cg ^ sw) << 3)];         \
      bf16x8 v1 = *(const bf16x8*)&lds[(VO) + (32 + l31) * 64 + ((cg ^ sw) << 3)];  \
      u32 A0 = w40[2 * m2][0], A2 = w40[2 * m2 + 1][0];                             \
      pl32swap(A0, A2);                                                             \
      u32 A1 = w40[2 * m2][1], A3 = w40[2 * m2 + 1][1];                             \
      pl32swap(A1, A3);                                                             \
      union { u32 u[4]; bf16x8 v; } pf0;                                            \
      pf0.u[0] = A0; pf0.u[1] = A1; pf0.u[2] = A2; pf0.u[3] = A3;                   \
      acc00 = __builtin_amdgcn_mfma_f32_32x32x16_bf16(v0, pf0.v, acc00, 0, 0, 0);   \
      acc01 = __builtin_amdgcn_mfma_f32_32x32x16_bf16(v1, pf0.v, acc01, 0, 0, 0);   \
      u32 B0 = w41[2 * m2][0], B2 = w41[2 * m2 + 1][0];                             \
      pl32swap(B0, B2);                                                             \
      u32 B1 = w41[2 * m2][1], B3 = w41[2 * m2 + 1][1];                             \
      pl32swap(B1, B3);                                                             \
      union { u32 u[4]; bf16x8 v; } pf1;                                            \
      pf1.u[0] = B0; pf1.u[1] = B1; pf1.u[2] = B2; pf1.u[3] = B3;                   \
      acc10 = __builtin_amdgcn_mfma_f32_32x32x16_bf16(v0, pf1.v, acc10, 0, 0, 0);   \
      acc11 = __builtin_amdgcn_mfma_f32_32x32x16_bf16(v1, pf1.v, acc11, 0, 0, 0);   \
    }                                                                               \
    __builtin_amdgcn_s_setprio(0);                                                  \
  } while (0)

  // prologue: XL tile 0 -> A
  STAGE_XL(0, 8192);
  for (int j = 0; j < 15; ++j) {
    __syncthreads();
    STAGE_XL(4096, 12288);
    COMPUTE(0, 8192);
    __syncthreads();
    STAGE_XL(0, 8192);
    COMPUTE(4096, 12288);
  }
  __syncthreads();
  STAGE_XL(4096, 12288);   // stage XL 31
  COMPUTE(0, 8192);        // compute XL 30
  __syncthreads();
  STAGE_NEW(0, 8192);      // stage NEW 0
  COMPUTE(4096, 12288);    // compute XL 31
  for (int j = 0; j < 15; ++j) {
    __syncthreads();
    STAGE_NEW(4096, 12288);
    COMPUTE(0, 8192);
    __syncthreads();
    STAGE_NEW(0, 8192);
    COMPUTE(4096, 12288);
  }
  __syncthreads();
  STAGE_NEW(4096, 12288);  // stage NEW 31
  COMPUTE(0, 8192);        // compute NEW 30
  __syncthreads();
  COMPUTE(4096, 12288);    // compute NEW 31
#undef STAGE_XL
#undef STAGE_NEW
#undef COMPUTE

  // ---- combine ks partials in-block via LDS, normalize + transpose + store ----
  float lt0 = lrun0 + __shfl_xor(lrun0, 32);
  float lt1 = lrun1 + __shfl_xor(lrun1, 32);
  __syncthreads();
  float* CB = (float*)lds;  // 256 slots x 32 f32 = 32 KB; slot = (qt*2+qb)*64 + lane
  if (ks) {
    float* p0 = CB + (size_t)(qt * 2 + 0) * 64 * 32 + (size_t)lane * 32;
    float* p1 = CB + (size_t)(qt * 2 + 1) * 64 * 32 + (size_t)lane * 32;
#pragma unroll
    for (int j = 0; j < 8; j++) {
      f32x4 u0, u1;
#pragma unroll
      for (int e = 0; e < 4; e++) {
        u0[e] = (j < 4) ? acc00[4 * j + e] : acc01[4 * (j - 4) + e];
        u1[e] = (j < 4) ? acc10[4 * j + e] : acc11[4 * (j - 4) + e];
      }
      *(f32x4*)&p0[4 * (j ^ (lane & 7))] = u0;
      *(f32x4*)&p1[4 * (j ^ (lane & 7))] = u1;
    }
    if (hi == 0) {
      CBl[(qt * 2 + 0) * 32 + l31] = lt0;
      CBl[(qt * 2 + 1) * 32 + l31] = lt1;
    }
  }
  __syncthreads();
  if (!ks) {
    const float* p0 = CB + (size_t)(qt * 2 + 0) * 64 * 32 + (size_t)lane * 32;
    const float* p1 = CB + (size_t)(qt * 2 + 1) * 64 * 32 + (size_t)lane * 32;
#pragma unroll
    for (int j = 0; j < 8; j++) {
      f32x4 u0 = *(const f32x4*)&p0[4 * (j ^ (lane & 7))];
      f32x4 u1 = *(const f32x4*)&p1[4 * (j ^ (lane & 7))];
#pragma unroll
      for (int e = 0; e < 4; e++) {
        if (j < 4) { acc00[4 * j + e] += u0[e]; acc10[4 * j + e] += u1[e]; }
        else       { acc01[4 * (j - 4) + e] += u0[e]; acc11[4 * (j - 4) + e] += u1[e]; }
      }
    }
    lt0 += CBl[(qt * 2 + 0) * 32 + l31];
    lt1 += CBl[(qt * 2 + 1) * 32 + l31];
    float inv0 = 1.0f / lt0;
    float inv1 = 1.0f / lt1;
#pragma unroll
    for (int qb = 0; qb < 2; qb++) {
      float inv = qb ? inv1 : inv0;
      u16* Ts = (u16*)((char*)lds + (qt * 2 + qb) * 8192);  // 32 q x 64 d, chunk-XOR swizzled
#pragma unroll
      for (int dt = 0; dt < 2; dt++)
#pragma unroll
        for (int r2 = 0; r2 < 4; r2++) {
          u16x4 o;
#pragma unroll
          for (int e = 0; e < 4; e++) {
            float v;
            if (qb == 0) v = dt ? acc01[4 * r2 + e] : acc00[4 * r2 + e];
            else         v = dt ? acc11[4 * r2 + e] : acc10[4 * r2 + e];
            o[e] = f2bf(v * inv);
          }
          int dbase = dt * 32 + r2 * 8 + hi * 4;
          int byteoff = l31 * 128 + ((dbase * 2) ^ (sw << 4));
          *(u16x4*)((char*)Ts + byteoff) = o;
        }
#pragma unroll
      for (int p4 = 0; p4 < 4; p4++) {
        int row = p4 * 8 + (lane >> 3);
        int c16 = lane & 7;
        u16x8 v = *(const u16x8*)((const char*)Ts + row * 128 + ((c16 << 4) ^ ((row & 7) << 4)));
        *(u16x8*)&Y[((size_t)(b * T + q0 + qt * 64 + qb * 32 + row)) * 1024 + h * 64 + c16 * 8] = v;
      }
    }
  }
}

extern "C" void kernel_launch(void* const* d_in, const int* in_sizes, int n_in,
                              void* d_out, int out_size, void* d_ws, size_t ws_size,
                              hipStream_t stream) {
  const float* q = (const float*)d_in[0];
  const float* k_xl = (const float*)d_in[1];
  const float* v_xl = (const float*)d_in[2];
  const float* W_qkv = (const float*)d_in[3];
  const float* W_proj = (const float*)d_in[4];
  const float* pos = (const float*)d_in[5];

  u16* wqkv = (u16*)d_ws;                       // 3072*1024
  u16* wproj = wqkv + (size_t)3072 * 1024;      // 1024*1024
  u16* qbf = wproj + (size_t)1024 * 1024;       // 4096*1024
  u16* qkvb = qbf + (size_t)4096 * 1024;        // 4096*3072
  u16* khxl = qkvb + (size_t)4096 * 3072;       // 32*2048*64
  u16* vt = khxl + (size_t)4 * 1024 * 1024;     // 32*64*4096
  u16* ybf = vt + (size_t)8 * 1024 * 1024;      // 4096*1024

  const float SC = 0.125f * 1.4426950408889634f;  // 1/sqrt(64) * log2(e)

  cvt_fuse<<<10240, 256, 0, stream>>>(q, W_qkv, W_proj, k_xl, pos, qbf, wqkv, wproj, khxl, SC);

  gemm_bt4<1><<<dim3(24, 32), 256, 0, stream>>>(qbf, wqkv, qkvb, 4096, 3072, 1024);

  build_vt<<<dim3(64, 32), 256, 0, stream>>>(v_xl, qkvb, vt);

  attn_fwd10<<<dim3(16, 32), 256, 0, stream>>>(qkvb, khxl, vt, ybf);

  gemm_bt4<0><<<dim3(8, 32), 256, 0, stream>>>(ybf, wproj, d_out, 4096, 1024, 1024);
}